// Round 11
// baseline (132.812 us; speedup 1.0000x reference)
//
#include <hip/hip_runtime.h>
#include <hip/hip_bf16.h>
#include <math.h>
#include <stdint.h>

#define Bd 2
#define Nd 1024
#define Dd 1024
#define Hh 16
#define EPSf 1e-6f

typedef short s8v __attribute__((ext_vector_type(8)));
typedef float f16v __attribute__((ext_vector_type(16)));
typedef float f4v __attribute__((ext_vector_type(4)));

#define MFMA32x32(A,B,C) __builtin_amdgcn_mfma_f32_32x32x16_bf16(A,B,C,0,0,0)
#define PKB(d,a,b) asm("v_cvt_pk_bf16_f32 %0, %1, %2" : "=v"(d) : "v"(a), "v"(b))
#define SWL(a,b) asm volatile("v_permlane32_swap_b32 %0, %1" : "+v"(a), "+v"(b))
#define RMAP(r) (((r) & 3) + 8 * ((r) >> 2))

__device__ __forceinline__ void gl_lds16(const void* g, void* l) {
    __builtin_amdgcn_global_load_lds((const __attribute__((address_space(1))) unsigned int*)g,
                                     (__attribute__((address_space(3))) unsigned int*)l, 16, 0, 0);
}

__device__ __forceinline__ unsigned short bf16bits(float v) {
    __hip_bfloat16 h = __float2bfloat16(v);
    return *(unsigned short*)&h;
}

// bank-conflict-free slot permutation: 8 consecutive lanes cover all 8 16B bank groups
__device__ __forceinline__ int posf(int l, int h) {
    return ((l & 3) << 1) | ((l >> 2) & 1) | (h << 3) | ((l >> 3) << 4);
}

// ---------------- Kernel 0: prep ----------------
__global__ __launch_bounds__(256) void prep_kernel(
    const float* __restrict__ Wv, const float* __restrict__ Wo, unsigned short* __restrict__ wcvt,
    const float* __restrict__ WE, const float* __restrict__ WS,
    const float* __restrict__ WH, const float* __restrict__ Wrff,
    unsigned short* __restrict__ wfH, unsigned short* __restrict__ wfL)
{
    int bid = blockIdx.x, tid = threadIdx.x;
    if (bid < 2048) {
        int i = (bid * 256 + tid) * 4;
        const float* s = (i < (1 << 20)) ? (Wv + i) : (Wo + (i - (1 << 20)));
        float4 v = *(const float4*)s;
        ushort4 o;
        o.x = bf16bits(v.x); o.y = bf16bits(v.y); o.z = bf16bits(v.z); o.w = bf16bits(v.w);
        *(ushort4*)(wcvt + i) = o;
    } else {
        int g = (bid - 2048) * 4 + (tid >> 6);        // 0..639
        int lane = tid & 63, l31 = lane & 31, h8 = lane >> 5;
        int h = g / 40, rem = g % 40, fg = rem >> 2, c = rem & 3;
        int f = fg * 32 + l31;
        unsigned int hw[4] = {0, 0, 0, 0}, lw[4] = {0, 0, 0, 0};
        #pragma unroll
        for (int j = 0; j < 8; j++) {
            int d = c * 16 + h8 * 8 + j;
            float wv_;
            if (f < 64)       wv_ = WE[(h * 64 + d) * 64 + f];
            else if (f < 128) wv_ = WS[(h * 64 + d) * 64 + (f - 64)];
            else if (f < 192) wv_ = WH[(h * 64 + d) * 64 + (f - 128)];
            else              wv_ = Wrff[(h * 64 + d) * 128 + (f - 192)];
            unsigned int hb = bf16bits(wv_);
            unsigned int hfb = hb << 16;
            float hf = *(float*)&hfb;
            unsigned int lb = bf16bits(wv_ - hf);
            hw[j >> 1] |= hb << ((j & 1) * 16);
            lw[j >> 1] |= lb << ((j & 1) * 16);
        }
        int off = g * 512 + posf(l31, h8) * 8;        // ushort units
        int4 th; th.x = (int)hw[0]; th.y = (int)hw[1]; th.z = (int)hw[2]; th.w = (int)hw[3];
        int4 tl; tl.x = (int)lw[0]; tl.y = (int)lw[1]; tl.z = (int)lw[2]; tl.w = (int)lw[3];
        *(int4*)(wfH + off) = th;
        *(int4*)(wfL + off) = tl;
    }
}

// ---------------- Kernel 1: MFMA witness projections ----------------
__global__ __launch_bounds__(256) void witness_kernel(
    const float* __restrict__ x, const int* __restrict__ mask,
    const float* __restrict__ bE, const float* __restrict__ bS,
    const float* __restrict__ bH, const float* __restrict__ brff,
    const unsigned short* __restrict__ wfH, const unsigned short* __restrict__ wfL,
    unsigned short* __restrict__ wit, float* __restrict__ sqo,
    unsigned short* __restrict__ xb)
{
    __shared__ __align__(16) float xw[128 * 68 + 320];
    float* biasL = xw + 128 * 68;

    int tid = threadIdx.x, lane = tid & 63, w = tid >> 6;
    int l31 = lane & 31, h8 = lane >> 5;
    int nt = blockIdx.x, h = blockIdx.y, b = blockIdx.z;
    int n0 = nt * 128;
    size_t bh = (size_t)b * Hh + h;

    #pragma unroll
    for (int i = 0; i < 32; i++) {
        int idx = i * 256 + tid;
        int row = idx >> 6, col = idx & 63;
        float xv = x[((size_t)(b * Nd + n0 + row)) * Dd + h * 64 + col];
        xw[row * 68 + col] = xv;
        xb[((size_t)(b * Nd + n0 + row)) * Dd + h * 64 + col] = bf16bits(xv);
    }
    if (tid < 320) {
        int f = tid;
        float bv_;
        if (f < 64)       bv_ = bE[h * 64 + f];
        else if (f < 128) bv_ = bS[h * 64 + f - 64];
        else if (f < 192) bv_ = bH[h * 64 + f - 128];
        else              bv_ = brff[h * 128 + f - 192];
        biasL[f] = bv_;
    }
    __syncthreads();

    int tok = w * 32 + l31;
    s8v bxh[4], bxl[4];
    #pragma unroll
    for (int c = 0; c < 4; c++) {
        const float* xp = &xw[tok * 68 + c * 16 + h8 * 8];
        float4 u0 = *(const float4*)xp;
        float4 u1 = *(const float4*)(xp + 4);
        float e[8] = {u0.x, u0.y, u0.z, u0.w, u1.x, u1.y, u1.z, u1.w};
        unsigned int hwv[4], lwv[4];
        #pragma unroll
        for (int k = 0; k < 4; k++) {
            unsigned int hb0 = bf16bits(e[2 * k]), hb1 = bf16bits(e[2 * k + 1]);
            unsigned int f0b = hb0 << 16, f1b = hb1 << 16;
            float f0 = *(float*)&f0b, f1 = *(float*)&f1b;
            unsigned int lb0 = bf16bits(e[2 * k] - f0), lb1 = bf16bits(e[2 * k + 1] - f1);
            hwv[k] = hb0 | (hb1 << 16);
            lwv[k] = lb0 | (lb1 << 16);
        }
        int4 th; th.x = (int)hwv[0]; th.y = (int)hwv[1]; th.z = (int)hwv[2]; th.w = (int)hwv[3];
        int4 tl; tl.x = (int)lwv[0]; tl.y = (int)lwv[1]; tl.z = (int)lwv[2]; tl.w = (int)lwv[3];
        bxh[c] = *(s8v*)&th;
        bxl[c] = *(s8v*)&tl;
    }

    const char* wfh = (const char*)wfH + (size_t)h * 40960;
    const char* wfl = (const char*)wfL + (size_t)h * 40960;
    int loff = posf(l31, h8) * 16;
    char* witg = (char*)wit + bh * 655360 + (size_t)(nt * 4 + w) * 20480;
    int R0 = 4 * h8;

    auto proj = [&](int fg) -> f16v {
        f16v acc = {};
        #pragma unroll
        for (int c = 0; c < 4; c++) {
            s8v aH_ = *(const s8v*)(wfh + ((fg * 4 + c) << 10) + loff);
            s8v aL_ = *(const s8v*)(wfl + ((fg * 4 + c) << 10) + loff);
            acc = MFMA32x32(aH_, bxh[c], acc);
            acc = MFMA32x32(aL_, bxh[c], acc);
            acc = MFMA32x32(aH_, bxl[c], acc);
        }
        return acc;
    };

    auto emit = [&](const float* vv, int cc0, float* sqp) {
        unsigned int p0, p1, p2, p3, p4, p5, p6, p7;
        PKB(p0, vv[0], vv[1]);   PKB(p1, vv[2], vv[3]);
        PKB(p2, vv[4], vv[5]);   PKB(p3, vv[6], vv[7]);
        PKB(p4, vv[8], vv[9]);   PKB(p5, vv[10], vv[11]);
        PKB(p6, vv[12], vv[13]); PKB(p7, vv[14], vv[15]);
        if (sqp) {
            float s = *sqp;
            unsigned int ws_[8] = {p0, p1, p2, p3, p4, p5, p6, p7};
            #pragma unroll
            for (int k = 0; k < 8; k++) {
                unsigned int lobits = ws_[k] << 16, hibits = ws_[k] & 0xffff0000u;
                float lo = *(float*)&lobits, hi = *(float*)&hibits;
                s = fmaf(lo, lo, fmaf(hi, hi, s));
            }
            *sqp = s;
        }
        SWL(p0, p2); SWL(p1, p3); SWL(p4, p6); SWL(p5, p7);
        int4 t1; t1.x = (int)p0; t1.y = (int)p1; t1.z = (int)p2; t1.w = (int)p3;
        int4 t2; t2.x = (int)p4; t2.y = (int)p5; t2.z = (int)p6; t2.w = (int)p7;
        *(int4*)(witg + cc0 * 1024 + loff) = t1;
        *(int4*)(witg + cc0 * 1024 + 1024 + loff) = t2;
    };

    float vv[16];

    float sE_ = 0.f;
    {
        f16v a0 = proj(0);
        #pragma unroll
        for (int r = 0; r < 16; r++) vv[r] = a0[r] + biasL[0 + RMAP(r) + R0];
        emit(vv, 0, &sE_);
        f16v a1 = proj(1);
        #pragma unroll
        for (int r = 0; r < 16; r++) vv[r] = a1[r] + biasL[32 + RMAP(r) + R0];
        emit(vv, 2, &sE_);
    }
    sE_ += __shfl_xor(sE_, 32, 64);

    {
        f16v a2 = proj(2), a3 = proj(3);
        float v2[16], v3[16], ns = 0.f;
        #pragma unroll
        for (int r = 0; r < 16; r++) {
            v2[r] = a2[r] + biasL[64 + RMAP(r) + R0];
            v3[r] = a3[r] + biasL[96 + RMAP(r) + R0];
            ns = fmaf(v2[r], v2[r], fmaf(v3[r], v3[r], ns));
        }
        ns += __shfl_xor(ns, 32, 64);
        float inv = __builtin_amdgcn_rcpf(sqrtf(ns) + EPSf);
        #pragma unroll
        for (int r = 0; r < 16; r++) { v2[r] *= inv; v3[r] *= inv; }
        emit(v2, 4, nullptr);
        emit(v3, 6, nullptr);
    }

    float s2_ = 0.f, sq2v;
    {
        f16v a4 = proj(4), a5 = proj(5);
        float u4[16], u5[16], us = 0.f;
        #pragma unroll
        for (int r = 0; r < 16; r++) {
            u4[r] = a4[r] + biasL[128 + RMAP(r) + R0];
            u5[r] = a5[r] + biasL[160 + RMAP(r) + R0];
            us = fmaf(u4[r], u4[r], fmaf(u5[r], u5[r], us));
        }
        us += __shfl_xor(us, 32, 64);
        float un = sqrtf(us);
        float sc = tanhf(un) * __builtin_amdgcn_rcpf(un + EPSf);
        #pragma unroll
        for (int r = 0; r < 16; r++) { u4[r] *= sc; u5[r] *= sc; }
        emit(u4, 8, &s2_);
        emit(u5, 10, &s2_);
    }
    s2_ += __shfl_xor(s2_, 32, 64);
    sq2v = 1.f - fminf(fmaxf(s2_, 0.f), 1.f - 1e-5f);

    float zq = 0.f;
    #pragma unroll
    for (int fg = 6; fg < 10; fg++) {
        f16v af = proj(fg);
        #pragma unroll
        for (int r = 0; r < 16; r++)
            vv[r] = 0.125f * __cosf(af[r] + biasL[fg * 32 + RMAP(r) + R0]);
        emit(vv, (fg - 6) * 2 + 12, &zq);
    }
    zq += __shfl_xor(zq, 32, 64);

    if (h8 == 0) {
        int m = mask[b * Nd + n0 + tok];
        f4v s4;
        s4.x = sE_ + ((m > 0) ? 0.f : 2e9f);
        s4.y = s2_;
        s4.z = sq2v;
        s4.w = zq;
        *(f4v*)(sqo + ((bh << 10) + n0 + tok) * 4) = s4;
    }
}

// ---------------- bf16 MFMA GEMM: C[M x 1024] = A[M x 1024] * W[1024 x 1024]^T + bias ----------------
// BM=64 x BN=128 tile, BK=64, 256 threads (4 waves: wm=row-half, wn=col-half; each wave
// 32 rows x 64 cols = 2 subtiles of 32x32 -> 8 MFMAs/wave/kt). XOR-swizzled LDS, dbuf.
// MODE 0: f32 row-major to outF.  MODE 1: bf16 fragment-major vt2 (coalesced via LDS buffer).
template<int MODE>
__global__ __launch_bounds__(256) void gemm_bf16_kernel(
    const unsigned short* __restrict__ A, const unsigned short* __restrict__ Bw,
    const float* __restrict__ bias, float* __restrict__ outF, unsigned short* __restrict__ outV)
{
    __shared__ __align__(16) char sm[49152];   // 2 x (At 8KB + Bt 16KB)
    int tid = threadIdx.x, lane = tid & 63;
    int w = tid >> 6, wm = w & 1, wn = w >> 1;
    int h8 = lane >> 5, l31 = lane & 31;
    int i0 = blockIdx.y * 64, j0 = blockIdx.x * 128;
    const char* Ab = (const char*)A;
    const char* Bb = (const char*)Bw;

    f16v acc0 = {}, acc1 = {};

    auto stage = [&](int kt, int buf) {
        char* atb = sm + buf * 24576;
        char* btb = atb + 8192;
        #pragma unroll
        for (int j = 0; j < 2; j++) {
            int elem = j * 256 + tid;
            int row = elem >> 3, u = elem & 7;
            int so = (u * 16) ^ ((row & 7) << 4);
            gl_lds16(Ab + (size_t)(i0 + row) * 2048 + kt * 128 + so, atb + elem * 16);
        }
        #pragma unroll
        for (int j = 0; j < 4; j++) {
            int elem = j * 256 + tid;
            int row = elem >> 3, u = elem & 7;
            int so = (u * 16) ^ ((row & 7) << 4);
            gl_lds16(Bb + (size_t)(j0 + row) * 2048 + kt * 128 + so, btb + elem * 16);
        }
    };

    stage(0, 0);
    __syncthreads();
    for (int kt = 0; kt < 16; kt++) {
        int buf = kt & 1;
        if (kt < 15) stage(kt + 1, buf ^ 1);
        const char* atb = sm + buf * 24576;
        const char* btb = atb + 8192;
        int swz = (l31 & 7) << 4;
        #pragma unroll
        for (int kk = 0; kk < 4; kk++) {
            int ko = (kk * 32 + h8 * 16) ^ swz;
            s8v a  = *(const s8v*)(atb + (wm * 32 + l31) * 128 + ko);
            s8v b0 = *(const s8v*)(btb + (wn * 64 + l31) * 128 + ko);
            s8v b1 = *(const s8v*)(btb + (wn * 64 + 32 + l31) * 128 + ko);
            acc0 = MFMA32x32(a, b0, acc0);
            acc1 = MFMA32x32(a, b1, acc1);
        }
        __syncthreads();
    }

    if (MODE == 0) {
        #pragma unroll
        for (int r = 0; r < 16; r++) {
            int rf = RMAP(r) + 4 * h8;
            int grow = i0 + wm * 32 + rf;
            int gc0 = j0 + wn * 64 + l31;
            outF[(size_t)grow * 1024 + gc0] = acc0[r] + bias[gc0];
            outF[(size_t)grow * 1024 + gc0 + 32] = acc1[r] + bias[gc0 + 32];
        }
    } else {
        // vt2[bh][kblk][chunk=kh*2+dh][posf(d&31, (k&15)>>3)*8 + (k&7)]
        unsigned short* vbuf = (unsigned short*)sm;  // 4 groups (wn*2+wm) x 2048 ushorts = 16KB
        int gc0 = j0 + wn * 64 + l31;
        float bb0 = bias[gc0], bb1 = bias[gc0 + 32];
        int base = (wn * 2 + wm) * 2048;
        #pragma unroll
        for (int r = 0; r < 16; r++) {
            int rf = RMAP(r) + 4 * h8;                 // token within 32-row group; k = rf
            int kh = rf >> 4, h8k = (rf >> 3) & 1, jj = rf & 7;
            vbuf[base + (kh * 2 + 0) * 512 + posf(l31, h8k) * 8 + jj] = bf16bits(acc0[r] + bb0);
            vbuf[base + (kh * 2 + 1) * 512 + posf(l31, h8k) * 8 + jj] = bf16bits(acc1[r] + bb1);
        }
        __syncthreads();
        int nloc = i0 & 1023;
        #pragma unroll
        for (int j = 0; j < 4; j++) {
            int sid = j * 256 + tid;                  // 0..1023 16B-slots
            int g = sid >> 8, wn2 = g >> 1, wm2 = g & 1;
            int chunk = (sid >> 6) & 3, slot = sid & 63;
            int bh2 = (i0 >> 10) * 16 + (j0 >> 6) + wn2;
            int kblkg = (nloc >> 5) + wm2;
            *(int4*)((char*)outV + (size_t)bh2 * 131072 + kblkg * 4096 + chunk * 1024 + slot * 16)
                = *(const int4*)((const char*)sm + sid * 16);
        }
    }
}

// ---------------- Kernel 3: MFMA distances + online softmax + MFMA PV ----------------
// round-8 version (stable: 83.6 us, no spills).
__global__ __launch_bounds__(256, 4) void attn_kernel(
    const unsigned short* __restrict__ wit, const float* __restrict__ sqb,
    const unsigned short* __restrict__ vt,
    const float* __restrict__ al_, const float* __restrict__ be_,
    const float* __restrict__ ga_, const float* __restrict__ de_,
    const float* __restrict__ tp_,
    __hip_bfloat16* __restrict__ aout)
{
    __shared__ __align__(16) char sm[36864];
    int tid = threadIdx.x, lane = tid & 63;
    int par = tid >> 6;
    int h8 = lane >> 5, l31 = lane & 31, h4 = h8 * 4;

    int bid = blockIdx.x;
    int xcd = bid & 7, slot = bid >> 3;
    int bh = (xcd << 2) | (slot >> 5);
    int qt = slot & 31;
    int bz = bh >> 4, hh = bh & 15;
    int q0 = qt * 32;

    const char* witb = (const char*)wit + (size_t)bh * 655360;
    const char* vtb = (const char*)vt + (size_t)bh * 131072;

    float* sqAll = (float*)sm;
    char* qlds = sm + 16384;

    #pragma unroll
    for (int j = 0; j < 4; j++) {
        int blk = par * 4 + j;
        gl_lds16((const char*)sqb + (size_t)bh * 16384 + blk * 1024 + lane * 16,
                 sm + blk * 1024);
    }
    #pragma unroll
    for (int j = 0; j < 5; j++) {
        int ch = par * 5 + j;
        gl_lds16(witb + (size_t)qt * 20480 + ch * 1024 + lane * 16,
                 qlds + ch * 1024);
    }

    int laneoff = posf(l31, h8) * 16;

    f4v sqq = *(const f4v*)(sqb + ((size_t)bh * Nd + q0 + l31) * 4);
    const float LOG2E = 1.4426950408889634f;
    const float LN2 = 0.6931471805599453f;
    float itmp2 = LOG2E / tp_[hh];
    float al2 = -al_[hh] * itmp2;
    float be2 = -be_[hh] * itmp2;
    float de2 = -de_[hh] * itmp2;
    float gl2 = -ga_[hh] * itmp2 * LN2;
    float sqqxE = sqq.x + EPSf, sqqwE = sqq.w + EPSf;
    float sqqy = sqq.y, sqqz = sqq.z;

    float m_run = -INFINITY, l_run = 0.f;
    f16v o0 = {}, o1 = {};

    __syncthreads();

    for (int it = 0; it < 8; it++) {
        int kblk = it * 4 + par;
        int k0 = kblk * 32;
        const char* kp = witb + (size_t)kblk * 20480 + laneoff;
        float p[16];

        {
            __builtin_amdgcn_s_setprio(1);
            f16v aE = {}, aS = {};
            #pragma unroll
            for (int c = 0; c < 8; c++) {
                s8v a = *(const s8v*)(kp + c * 1024);
                s8v q = *(const s8v*)(qlds + c * 1024 + laneoff);
                if (c < 4) aE = MFMA32x32(a, q, aE);
                else       aS = MFMA32x32(a, q, aS);
            }
            __builtin_amdgcn_s_setprio(0);
            #pragma unroll
            for (int r = 0; r < 16; r++) {
                int kr = RMAP(r) + h4;
                float skx = sqAll[(size_t)(k0 + kr) * 4];
                float sE = fmaxf(fmaf(-2.f, aE[r], sqqxE + skx), EPSf);
                float dE = __builtin_amdgcn_sqrtf(sE);
                float cv = aS[r];
                float ax = fminf(fabsf(cv), 1.f - EPSf);
                float sq1 = __builtin_amdgcn_sqrtf(1.f - ax);
                float pa = sq1 * fmaf(ax, fmaf(ax, fmaf(ax, -0.0187293f, 0.0742610f), -0.2121144f), 1.5707288f);
                float dS = (cv < 0.f) ? (3.14159265f - pa) : pa;
                p[r] = fmaf(al2, dE, be2 * dS);
            }
        }

        {
            __builtin_amdgcn_s_setprio(1);
            f16v aH = {}, aF = {};
            #pragma unroll
            for (int c = 8; c < 20; c++) {
                s8v a = *(const s8v*)(kp + c * 1024);
                s8v q = *(const s8v*)(qlds + c * 1024 + laneoff);
                if (c < 12) aH = MFMA32x32(a, q, aH);
                else        aF = MFMA32x32(a, q, aF);
            }
            __builtin_amdgcn_s_setprio(0);
            #pragma unroll
            for (int r = 0; r < 16; r++) {
                int kr = RMAP(r) + h4;
                const float4 sk = *(const float4*)(sqAll + (size_t)(k0 + kr) * 4);
                float d2 = fmaxf(fmaf(-2.f, aH[r], sqqy + sk.y), 0.f);
                float den = fmaf(sqqz, sk.z, EPSf);
                float arx = fmaxf(fmaf(d2 + d2, __builtin_amdgcn_rcpf(den), 1.f), 1.f + EPSf);
                float sh = __builtin_amdgcn_sqrtf(fmaf(arx, arx, -1.f));
                float lH = log2f(arx + sh);
                float sF = fmaxf(fmaf(-2.f, aF[r], sqqwE + sk.w), EPSf);
                float dF = __builtin_amdgcn_sqrtf(sF);
                p[r] = fmaf(de2, dF, fmaf(gl2, lH, p[r]));
            }
        }

        const char* vp = vtb + (size_t)kblk * 4096 + laneoff;
        s8v b00 = *(const s8v*)(vp);
        s8v b01 = *(const s8v*)(vp + 1024);
        s8v b10 = *(const s8v*)(vp + 2048);
        s8v b11 = *(const s8v*)(vp + 3072);

        float mt = p[0];
        #pragma unroll
        for (int r = 1; r < 16; r++) mt = fmaxf(mt, p[r]);
        mt = fmaxf(mt, __shfl_xor(mt, 32, 64));
        if (!__all(mt <= m_run + 8.f)) {
            float mnew = fmaxf(m_run, mt);
            float sc = exp2f(m_run - mnew);
            l_run *= sc;
            m_run = mnew;
            #pragma unroll
            for (int r = 0; r < 16; r++) {
                float s = __shfl(sc, RMAP(r) + h4, 64);
                o0[r] *= s; o1[r] *= s;
            }
        }
        float ps = 0.f;
        #pragma unroll
        for (int r = 0; r < 16; r++) { p[r] = exp2f(p[r] - m_run); ps += p[r]; }
        ps += __shfl_xor(ps, 32, 64);
        l_run += ps;

        unsigned int w0, w1, w2, w3, y0, y1, y2, y3;
        PKB(w0, p[0], p[1]);   PKB(w1, p[2], p[3]);
        PKB(w2, p[4], p[5]);   PKB(w3, p[6], p[7]);
        PKB(y0, p[8], p[9]);   PKB(y1, p[10], p[11]);
        PKB(y2, p[12], p[13]); PKB(y3, p[14], p[15]);
        SWL(w0, w2); SWL(w1, w3); SWL(y0, y2); SWL(y1, y3);
        int4 t1; t1.x = (int)w0; t1.y = (int)w1; t1.z = (int)w2; t1.w = (int)w3;
        int4 t2; t2.x = (int)y0; t2.y = (int)y1; t2.z = (int)y2; t2.w = (int)y3;
        s8v A1 = *(s8v*)&t1;
        s8v A2 = *(s8v*)&t2;

        __builtin_amdgcn_s_setprio(1);
        o0 = MFMA32x32(A1, b00, o0);
        o0 = MFMA32x32(A2, b10, o0);
        o1 = MFMA32x32(A1, b01, o1);
        o1 = MFMA32x32(A2, b11, o1);
        __builtin_amdgcn_s_setprio(0);
    }

    float* slotO0 = (float*)sm;
    float* slotO1 = (float*)(sm + 8192);
    float* slotM0 = (float*)(sm + 16384);
    float* slotM1 = (float*)(sm + 16896);

    __syncthreads();
    if (par >= 2) {
        float* so = (par == 2) ? slotO0 : slotO1;
        float* sM = (par == 2) ? slotM0 : slotM1;
        #pragma unroll
        for (int r = 0; r < 16; r++) {
            int qr = RMAP(r) + h4;
            so[qr * 64 + l31] = o0[r];
            so[qr * 64 + 32 + l31] = o1[r];
        }
        if (lane < 32) { sM[lane] = m_run; sM[32 + lane] = l_run; }
    }
    __syncthreads();
    if (par < 2) {
        float* so = (par == 0) ? slotO0 : slotO1;
        float* sM = (par == 0) ? slotM0 : slotM1;
        float m2 = sM[l31], l2 = sM[32 + l31];
        float M = fmaxf(m_run, m2);
        float s1 = exp2f(m_run - M), s2 = exp2f(m2 - M);
        l_run = l_run * s1 + l2 * s2;
        m_run = M;
        #pragma unroll
        for (int r = 0; r < 16; r++) {
            int qr = RMAP(r) + h4;
            float a = __shfl(s1, qr, 64), b = __shfl(s2, qr, 64);
            o0[r] = o0[r] * a + so[qr * 64 + l31] * b;
            o1[r] = o1[r] * a + so[qr * 64 + 32 + l31] * b;
        }
    }
    __syncthreads();
    if (par == 1) {
        #pragma unroll
        for (int r = 0; r < 16; r++) {
            int qr = RMAP(r) + h4;
            slotO0[qr * 64 + l31] = o0[r];
            slotO0[qr * 64 + 32 + l31] = o1[r];
        }
        if (lane < 32) { slotM0[lane] = m_run; slotM0[32 + lane] = l_run; }
    }
    __syncthreads();
    if (par == 0) {
        float m2 = slotM0[l31], l2 = slotM0[32 + l31];
        float M = fmaxf(m_run, m2);
        float s1 = exp2f(m_run - M), s2 = exp2f(m2 - M);
        float lt = l_run * s1 + l2 * s2;
        float inv = 1.f / lt;
        float a0 = s1 * inv, b0 = s2 * inv;
        #pragma unroll
        for (int r = 0; r < 16; r++) {
            int qr = RMAP(r) + h4;
            float a = __shfl(a0, qr, 64), b = __shfl(b0, qr, 64);
            float r0 = o0[r] * a + slotO0[qr * 64 + l31] * b;
            float r1 = o1[r] * a + slotO0[qr * 64 + 32 + l31] * b;
            size_t row = (size_t)bz * Nd + q0 + qr;
            aout[row * Dd + hh * 64 + l31] = __float2bfloat16(r0);
            aout[row * Dd + hh * 64 + 32 + l31] = __float2bfloat16(r1);
        }
    }
}

extern "C" void kernel_launch(void* const* d_in, const int* in_sizes, int n_in,
                              void* d_out, int out_size, void* d_ws, size_t ws_size,
                              hipStream_t stream) {
    const float* x    = (const float*)d_in[0];
    const int*   mask = (const int*)d_in[1];
    const float* WE   = (const float*)d_in[2];
    const float* bE   = (const float*)d_in[3];
    const float* WS   = (const float*)d_in[4];
    const float* bS   = (const float*)d_in[5];
    const float* WH   = (const float*)d_in[6];
    const float* bH   = (const float*)d_in[7];
    const float* Wrff = (const float*)d_in[8];
    const float* brff = (const float*)d_in[9];
    const float* alpha = (const float*)d_in[10];
    const float* beta  = (const float*)d_in[11];
    const float* gamma_ = (const float*)d_in[12];
    const float* delta = (const float*)d_in[13];
    const float* temperature = (const float*)d_in[14];
    const float* Wv = (const float*)d_in[15];
    const float* bv = (const float*)d_in[16];
    const float* Wo = (const float*)d_in[17];
    const float* bo = (const float*)d_in[18];

    char* ws = (char*)d_ws;
    unsigned short* wit = (unsigned short*)ws;               // 20971520
    float* sq  = (float*)(ws + 20971520);                    // 524288
    unsigned short* xb  = (unsigned short*)(ws + 21495808);  // 4194304
    unsigned short* wvb = (unsigned short*)(ws + 25690112);  // 2097152
    unsigned short* wob = (unsigned short*)(ws + 27787264);  // 2097152
    unsigned short* vt  = (unsigned short*)(ws + 29884416);  // 4194304
    __hip_bfloat16* aout = (__hip_bfloat16*)(ws + 34078720); // 4194304
    unsigned short* wfH = (unsigned short*)(ws + 34078720);            // 655360 B (dead before attn)
    unsigned short* wfL = (unsigned short*)(ws + 34078720 + 655360);   // 655360 B

    prep_kernel<<<dim3(2208), 256, 0, stream>>>(Wv, Wo, wvb, WE, WS, WH, Wrff, wfH, wfL);

    witness_kernel<<<dim3(8, 16, 2), 256, 0, stream>>>(
        x, mask, bE, bS, bH, brff, wfH, wfL, wit, sq, xb);

    gemm_bf16_kernel<1><<<dim3(8, 32), 256, 0, stream>>>(xb, wvb, bv, nullptr, vt);

    attn_kernel<<<dim3(1024), 256, 0, stream>>>(
        wit, sq, vt, alpha, beta, gamma_, delta, temperature, aout);

    gemm_bf16_kernel<0><<<dim3(8, 32), 256, 0, stream>>>(
        (const unsigned short*)aout, wob, bo, (float*)d_out, nullptr);
}

// Round 12
// 129.739 us; speedup vs baseline: 1.0237x; 1.0237x over previous
//
#include <hip/hip_runtime.h>
#include <hip/hip_bf16.h>
#include <math.h>
#include <stdint.h>

#define Bd 2
#define Nd 1024
#define Dd 1024
#define Hh 16
#define EPSf 1e-6f

typedef short s8v __attribute__((ext_vector_type(8)));
typedef float f16v __attribute__((ext_vector_type(16)));
typedef float f4v __attribute__((ext_vector_type(4)));

#define MFMA32x32(A,B,C) __builtin_amdgcn_mfma_f32_32x32x16_bf16(A,B,C,0,0,0)
#define PKB(d,a,b) asm("v_cvt_pk_bf16_f32 %0, %1, %2" : "=v"(d) : "v"(a), "v"(b))
#define SWL(a,b) asm volatile("v_permlane32_swap_b32 %0, %1" : "+v"(a), "+v"(b))
#define RMAP(r) (((r) & 3) + 8 * ((r) >> 2))

__device__ __forceinline__ void gl_lds16(const void* g, void* l) {
    __builtin_amdgcn_global_load_lds((const __attribute__((address_space(1))) unsigned int*)g,
                                     (__attribute__((address_space(3))) unsigned int*)l, 16, 0, 0);
}

__device__ __forceinline__ unsigned short bf16bits(float v) {
    __hip_bfloat16 h = __float2bfloat16(v);
    return *(unsigned short*)&h;
}

// bank-conflict-free slot permutation: 8 consecutive lanes cover all 8 16B bank groups
__device__ __forceinline__ int posf(int l, int h) {
    return ((l & 3) << 1) | ((l >> 2) & 1) | (h << 3) | ((l >> 3) << 4);
}

// ---------------- Kernel 0: prep ----------------
__global__ __launch_bounds__(256) void prep_kernel(
    const float* __restrict__ Wv, const float* __restrict__ Wo, unsigned short* __restrict__ wcvt,
    const float* __restrict__ WE, const float* __restrict__ WS,
    const float* __restrict__ WH, const float* __restrict__ Wrff,
    unsigned short* __restrict__ wfH, unsigned short* __restrict__ wfL)
{
    int bid = blockIdx.x, tid = threadIdx.x;
    if (bid < 2048) {
        int i = (bid * 256 + tid) * 4;
        const float* s = (i < (1 << 20)) ? (Wv + i) : (Wo + (i - (1 << 20)));
        float4 v = *(const float4*)s;
        ushort4 o;
        o.x = bf16bits(v.x); o.y = bf16bits(v.y); o.z = bf16bits(v.z); o.w = bf16bits(v.w);
        *(ushort4*)(wcvt + i) = o;
    } else {
        int g = (bid - 2048) * 4 + (tid >> 6);        // 0..639
        int lane = tid & 63, l31 = lane & 31, h8 = lane >> 5;
        int h = g / 40, rem = g % 40, fg = rem >> 2, c = rem & 3;
        int f = fg * 32 + l31;
        unsigned int hw[4] = {0, 0, 0, 0}, lw[4] = {0, 0, 0, 0};
        #pragma unroll
        for (int j = 0; j < 8; j++) {
            int d = c * 16 + h8 * 8 + j;
            float wv_;
            if (f < 64)       wv_ = WE[(h * 64 + d) * 64 + f];
            else if (f < 128) wv_ = WS[(h * 64 + d) * 64 + (f - 64)];
            else if (f < 192) wv_ = WH[(h * 64 + d) * 64 + (f - 128)];
            else              wv_ = Wrff[(h * 64 + d) * 128 + (f - 192)];
            unsigned int hb = bf16bits(wv_);
            unsigned int hfb = hb << 16;
            float hf = *(float*)&hfb;
            unsigned int lb = bf16bits(wv_ - hf);
            hw[j >> 1] |= hb << ((j & 1) * 16);
            lw[j >> 1] |= lb << ((j & 1) * 16);
        }
        int off = g * 512 + posf(l31, h8) * 8;        // ushort units
        int4 th; th.x = (int)hw[0]; th.y = (int)hw[1]; th.z = (int)hw[2]; th.w = (int)hw[3];
        int4 tl; tl.x = (int)lw[0]; tl.y = (int)lw[1]; tl.z = (int)lw[2]; tl.w = (int)lw[3];
        *(int4*)(wfH + off) = th;
        *(int4*)(wfL + off) = tl;
    }
}

// ---------------- Kernel 1: MFMA witness projections ----------------
__global__ __launch_bounds__(256) void witness_kernel(
    const float* __restrict__ x, const int* __restrict__ mask,
    const float* __restrict__ bE, const float* __restrict__ bS,
    const float* __restrict__ bH, const float* __restrict__ brff,
    const unsigned short* __restrict__ wfH, const unsigned short* __restrict__ wfL,
    unsigned short* __restrict__ wit, float* __restrict__ sqo,
    unsigned short* __restrict__ xb)
{
    __shared__ __align__(16) float xw[128 * 68 + 320];
    float* biasL = xw + 128 * 68;

    int tid = threadIdx.x, lane = tid & 63, w = tid >> 6;
    int l31 = lane & 31, h8 = lane >> 5;
    int nt = blockIdx.x, h = blockIdx.y, b = blockIdx.z;
    int n0 = nt * 128;
    size_t bh = (size_t)b * Hh + h;

    #pragma unroll
    for (int i = 0; i < 32; i++) {
        int idx = i * 256 + tid;
        int row = idx >> 6, col = idx & 63;
        float xv = x[((size_t)(b * Nd + n0 + row)) * Dd + h * 64 + col];
        xw[row * 68 + col] = xv;
        xb[((size_t)(b * Nd + n0 + row)) * Dd + h * 64 + col] = bf16bits(xv);
    }
    if (tid < 320) {
        int f = tid;
        float bv_;
        if (f < 64)       bv_ = bE[h * 64 + f];
        else if (f < 128) bv_ = bS[h * 64 + f - 64];
        else if (f < 192) bv_ = bH[h * 64 + f - 128];
        else              bv_ = brff[h * 128 + f - 192];
        biasL[f] = bv_;
    }
    __syncthreads();

    int tok = w * 32 + l31;
    s8v bxh[4], bxl[4];
    #pragma unroll
    for (int c = 0; c < 4; c++) {
        const float* xp = &xw[tok * 68 + c * 16 + h8 * 8];
        float4 u0 = *(const float4*)xp;
        float4 u1 = *(const float4*)(xp + 4);
        float e[8] = {u0.x, u0.y, u0.z, u0.w, u1.x, u1.y, u1.z, u1.w};
        unsigned int hwv[4], lwv[4];
        #pragma unroll
        for (int k = 0; k < 4; k++) {
            unsigned int hb0 = bf16bits(e[2 * k]), hb1 = bf16bits(e[2 * k + 1]);
            unsigned int f0b = hb0 << 16, f1b = hb1 << 16;
            float f0 = *(float*)&f0b, f1 = *(float*)&f1b;
            unsigned int lb0 = bf16bits(e[2 * k] - f0), lb1 = bf16bits(e[2 * k + 1] - f1);
            hwv[k] = hb0 | (hb1 << 16);
            lwv[k] = lb0 | (lb1 << 16);
        }
        int4 th; th.x = (int)hwv[0]; th.y = (int)hwv[1]; th.z = (int)hwv[2]; th.w = (int)hwv[3];
        int4 tl; tl.x = (int)lwv[0]; tl.y = (int)lwv[1]; tl.z = (int)lwv[2]; tl.w = (int)lwv[3];
        bxh[c] = *(s8v*)&th;
        bxl[c] = *(s8v*)&tl;
    }

    const char* wfh = (const char*)wfH + (size_t)h * 40960;
    const char* wfl = (const char*)wfL + (size_t)h * 40960;
    int loff = posf(l31, h8) * 16;
    char* witg = (char*)wit + bh * 655360 + (size_t)(nt * 4 + w) * 20480;
    int R0 = 4 * h8;

    auto proj = [&](int fg) -> f16v {
        f16v acc = {};
        #pragma unroll
        for (int c = 0; c < 4; c++) {
            s8v aH_ = *(const s8v*)(wfh + ((fg * 4 + c) << 10) + loff);
            s8v aL_ = *(const s8v*)(wfl + ((fg * 4 + c) << 10) + loff);
            acc = MFMA32x32(aH_, bxh[c], acc);
            acc = MFMA32x32(aL_, bxh[c], acc);
            acc = MFMA32x32(aH_, bxl[c], acc);
        }
        return acc;
    };

    auto emit = [&](const float* vv, int cc0, float* sqp) {
        unsigned int p0, p1, p2, p3, p4, p5, p6, p7;
        PKB(p0, vv[0], vv[1]);   PKB(p1, vv[2], vv[3]);
        PKB(p2, vv[4], vv[5]);   PKB(p3, vv[6], vv[7]);
        PKB(p4, vv[8], vv[9]);   PKB(p5, vv[10], vv[11]);
        PKB(p6, vv[12], vv[13]); PKB(p7, vv[14], vv[15]);
        if (sqp) {
            float s = *sqp;
            unsigned int ws_[8] = {p0, p1, p2, p3, p4, p5, p6, p7};
            #pragma unroll
            for (int k = 0; k < 8; k++) {
                unsigned int lobits = ws_[k] << 16, hibits = ws_[k] & 0xffff0000u;
                float lo = *(float*)&lobits, hi = *(float*)&hibits;
                s = fmaf(lo, lo, fmaf(hi, hi, s));
            }
            *sqp = s;
        }
        SWL(p0, p2); SWL(p1, p3); SWL(p4, p6); SWL(p5, p7);
        int4 t1; t1.x = (int)p0; t1.y = (int)p1; t1.z = (int)p2; t1.w = (int)p3;
        int4 t2; t2.x = (int)p4; t2.y = (int)p5; t2.z = (int)p6; t2.w = (int)p7;
        *(int4*)(witg + cc0 * 1024 + loff) = t1;
        *(int4*)(witg + cc0 * 1024 + 1024 + loff) = t2;
    };

    float vv[16];

    float sE_ = 0.f;
    {
        f16v a0 = proj(0);
        #pragma unroll
        for (int r = 0; r < 16; r++) vv[r] = a0[r] + biasL[0 + RMAP(r) + R0];
        emit(vv, 0, &sE_);
        f16v a1 = proj(1);
        #pragma unroll
        for (int r = 0; r < 16; r++) vv[r] = a1[r] + biasL[32 + RMAP(r) + R0];
        emit(vv, 2, &sE_);
    }
    sE_ += __shfl_xor(sE_, 32, 64);

    {
        f16v a2 = proj(2), a3 = proj(3);
        float v2[16], v3[16], ns = 0.f;
        #pragma unroll
        for (int r = 0; r < 16; r++) {
            v2[r] = a2[r] + biasL[64 + RMAP(r) + R0];
            v3[r] = a3[r] + biasL[96 + RMAP(r) + R0];
            ns = fmaf(v2[r], v2[r], fmaf(v3[r], v3[r], ns));
        }
        ns += __shfl_xor(ns, 32, 64);
        float inv = __builtin_amdgcn_rcpf(sqrtf(ns) + EPSf);
        #pragma unroll
        for (int r = 0; r < 16; r++) { v2[r] *= inv; v3[r] *= inv; }
        emit(v2, 4, nullptr);
        emit(v3, 6, nullptr);
    }

    float s2_ = 0.f, sq2v;
    {
        f16v a4 = proj(4), a5 = proj(5);
        float u4[16], u5[16], us = 0.f;
        #pragma unroll
        for (int r = 0; r < 16; r++) {
            u4[r] = a4[r] + biasL[128 + RMAP(r) + R0];
            u5[r] = a5[r] + biasL[160 + RMAP(r) + R0];
            us = fmaf(u4[r], u4[r], fmaf(u5[r], u5[r], us));
        }
        us += __shfl_xor(us, 32, 64);
        float un = sqrtf(us);
        float sc = tanhf(un) * __builtin_amdgcn_rcpf(un + EPSf);
        #pragma unroll
        for (int r = 0; r < 16; r++) { u4[r] *= sc; u5[r] *= sc; }
        emit(u4, 8, &s2_);
        emit(u5, 10, &s2_);
    }
    s2_ += __shfl_xor(s2_, 32, 64);
    sq2v = 1.f - fminf(fmaxf(s2_, 0.f), 1.f - 1e-5f);

    float zq = 0.f;
    #pragma unroll
    for (int fg = 6; fg < 10; fg++) {
        f16v af = proj(fg);
        #pragma unroll
        for (int r = 0; r < 16; r++)
            vv[r] = 0.125f * __cosf(af[r] + biasL[fg * 32 + RMAP(r) + R0]);
        emit(vv, (fg - 6) * 2 + 12, &zq);
    }
    zq += __shfl_xor(zq, 32, 64);

    if (h8 == 0) {
        int m = mask[b * Nd + n0 + tok];
        f4v s4;
        s4.x = sE_ + ((m > 0) ? 0.f : 2e9f);
        s4.y = s2_;
        s4.z = sq2v;
        s4.w = zq;
        *(f4v*)(sqo + ((bh << 10) + n0 + tok) * 4) = s4;
    }
}

// ---------------- bf16 MFMA GEMM (round-10 64x64 version) ----------------
template<int MODE>
__global__ __launch_bounds__(256) void gemm_bf16_kernel(
    const unsigned short* __restrict__ A, const unsigned short* __restrict__ Bw,
    const float* __restrict__ bias, float* __restrict__ outF, unsigned short* __restrict__ outV)
{
    __shared__ __align__(16) char sm[32768];
    int tid = threadIdx.x, lane = tid & 63;
    int w = tid >> 6, wm = w >> 1, wn = w & 1;
    int h8 = lane >> 5, l31 = lane & 31;
    int i0 = blockIdx.y * 64, j0 = blockIdx.x * 64;
    const char* Ab = (const char*)A;
    const char* Bb = (const char*)Bw;

    f16v acc = {};

    auto stage = [&](int kt, int buf) {
        char* atb = sm + buf * 16384;
        char* btb = atb + 8192;
        #pragma unroll
        for (int j = 0; j < 2; j++) {
            int elem = j * 256 + tid;
            int row = elem >> 3, u = elem & 7;
            int so = (u * 16) ^ ((row & 7) << 4);
            gl_lds16(Ab + (size_t)(i0 + row) * 2048 + kt * 128 + so, atb + elem * 16);
            gl_lds16(Bb + (size_t)(j0 + row) * 2048 + kt * 128 + so, btb + elem * 16);
        }
    };

    stage(0, 0);
    __syncthreads();
    for (int kt = 0; kt < 16; kt++) {
        int buf = kt & 1;
        if (kt < 15) stage(kt + 1, buf ^ 1);
        const char* atb = sm + buf * 16384;
        const char* btb = atb + 8192;
        int swz = (l31 & 7) << 4;
        #pragma unroll
        for (int kk = 0; kk < 4; kk++) {
            s8v a = *(const s8v*)(atb + (wm * 32 + l31) * 128 + ((kk * 32 + h8 * 16) ^ swz));
            s8v bq = *(const s8v*)(btb + (wn * 32 + l31) * 128 + ((kk * 32 + h8 * 16) ^ swz));
            acc = MFMA32x32(a, bq, acc);
        }
        __syncthreads();
    }

    if (MODE == 0) {
        #pragma unroll
        for (int r = 0; r < 16; r++) {
            int rf = RMAP(r) + 4 * h8;
            int grow = i0 + wm * 32 + rf;
            int gcol = j0 + wn * 32 + l31;
            outF[(size_t)grow * 1024 + gcol] = acc[r] + bias[gcol];
        }
    } else {
        unsigned short* vbuf = (unsigned short*)sm;
        int gcol = j0 + wn * 32 + l31;
        float bb = bias[gcol];
        #pragma unroll
        for (int r = 0; r < 16; r++) {
            int rf = RMAP(r) + 4 * h8;
            vbuf[wm * 2048 + ((rf >> 4) * 2 + wn) * 512 + posf(l31, (rf >> 3) & 1) * 8 + (rf & 7)]
                = bf16bits(acc[r] + bb);
        }
        __syncthreads();
        int bh2 = (i0 >> 10) * 16 + (j0 >> 6);
        int nloc = i0 & 1023;
        #pragma unroll
        for (int j = 0; j < 2; j++) {
            int sid = j * 256 + tid;
            int wm2 = sid >> 8, chunk = (sid >> 6) & 3, slot = sid & 63;
            int kblkg = ((nloc + wm2 * 32) >> 5);
            *(int4*)((char*)outV + (size_t)bh2 * 131072 + kblkg * 4096 + chunk * 1024 + slot * 16)
                = *(const int4*)((const char*)sm + sid * 16);
        }
    }
}

// ---------------- Kernel 3: MFMA distances + online softmax + MFMA PV ----------------
// round-8 version (stable: 83.6 us, no spills).
__global__ __launch_bounds__(256, 4) void attn_kernel(
    const unsigned short* __restrict__ wit, const float* __restrict__ sqb,
    const unsigned short* __restrict__ vt,
    const float* __restrict__ al_, const float* __restrict__ be_,
    const float* __restrict__ ga_, const float* __restrict__ de_,
    const float* __restrict__ tp_,
    __hip_bfloat16* __restrict__ aout)
{
    __shared__ __align__(16) char sm[36864];
    int tid = threadIdx.x, lane = tid & 63;
    int par = tid >> 6;
    int h8 = lane >> 5, l31 = lane & 31, h4 = h8 * 4;

    int bid = blockIdx.x;
    int xcd = bid & 7, slot = bid >> 3;
    int bh = (xcd << 2) | (slot >> 5);
    int qt = slot & 31;
    int bz = bh >> 4, hh = bh & 15;
    int q0 = qt * 32;

    const char* witb = (const char*)wit + (size_t)bh * 655360;
    const char* vtb = (const char*)vt + (size_t)bh * 131072;

    float* sqAll = (float*)sm;
    char* qlds = sm + 16384;

    #pragma unroll
    for (int j = 0; j < 4; j++) {
        int blk = par * 4 + j;
        gl_lds16((const char*)sqb + (size_t)bh * 16384 + blk * 1024 + lane * 16,
                 sm + blk * 1024);
    }
    #pragma unroll
    for (int j = 0; j < 5; j++) {
        int ch = par * 5 + j;
        gl_lds16(witb + (size_t)qt * 20480 + ch * 1024 + lane * 16,
                 qlds + ch * 1024);
    }

    int laneoff = posf(l31, h8) * 16;

    f4v sqq = *(const f4v*)(sqb + ((size_t)bh * Nd + q0 + l31) * 4);
    const float LOG2E = 1.4426950408889634f;
    const float LN2 = 0.6931471805599453f;
    float itmp2 = LOG2E / tp_[hh];
    float al2 = -al_[hh] * itmp2;
    float be2 = -be_[hh] * itmp2;
    float de2 = -de_[hh] * itmp2;
    float gl2 = -ga_[hh] * itmp2 * LN2;
    float sqqxE = sqq.x + EPSf, sqqwE = sqq.w + EPSf;
    float sqqy = sqq.y, sqqz = sqq.z;

    float m_run = -INFINITY, l_run = 0.f;
    f16v o0 = {}, o1 = {};

    __syncthreads();

    for (int it = 0; it < 8; it++) {
        int kblk = it * 4 + par;
        int k0 = kblk * 32;
        const char* kp = witb + (size_t)kblk * 20480 + laneoff;
        float p[16];

        {
            __builtin_amdgcn_s_setprio(1);
            f16v aE = {}, aS = {};
            #pragma unroll
            for (int c = 0; c < 8; c++) {
                s8v a = *(const s8v*)(kp + c * 1024);
                s8v q = *(const s8v*)(qlds + c * 1024 + laneoff);
                if (c < 4) aE = MFMA32x32(a, q, aE);
                else       aS = MFMA32x32(a, q, aS);
            }
            __builtin_amdgcn_s_setprio(0);
            #pragma unroll
            for (int r = 0; r < 16; r++) {
                int kr = RMAP(r) + h4;
                float skx = sqAll[(size_t)(k0 + kr) * 4];
                float sE = fmaxf(fmaf(-2.f, aE[r], sqqxE + skx), EPSf);
                float dE = __builtin_amdgcn_sqrtf(sE);
                float cv = aS[r];
                float ax = fminf(fabsf(cv), 1.f - EPSf);
                float sq1 = __builtin_amdgcn_sqrtf(1.f - ax);
                float pa = sq1 * fmaf(ax, fmaf(ax, fmaf(ax, -0.0187293f, 0.0742610f), -0.2121144f), 1.5707288f);
                float dS = (cv < 0.f) ? (3.14159265f - pa) : pa;
                p[r] = fmaf(al2, dE, be2 * dS);
            }
        }

        {
            __builtin_amdgcn_s_setprio(1);
            f16v aH = {}, aF = {};
            #pragma unroll
            for (int c = 8; c < 20; c++) {
                s8v a = *(const s8v*)(kp + c * 1024);
                s8v q = *(const s8v*)(qlds + c * 1024 + laneoff);
                if (c < 12) aH = MFMA32x32(a, q, aH);
                else        aF = MFMA32x32(a, q, aF);
            }
            __builtin_amdgcn_s_setprio(0);
            #pragma unroll
            for (int r = 0; r < 16; r++) {
                int kr = RMAP(r) + h4;
                const float4 sk = *(const float4*)(sqAll + (size_t)(k0 + kr) * 4);
                float d2 = fmaxf(fmaf(-2.f, aH[r], sqqy + sk.y), 0.f);
                float den = fmaf(sqqz, sk.z, EPSf);
                float arx = fmaxf(fmaf(d2 + d2, __builtin_amdgcn_rcpf(den), 1.f), 1.f + EPSf);
                float sh = __builtin_amdgcn_sqrtf(fmaf(arx, arx, -1.f));
                float lH = log2f(arx + sh);
                float sF = fmaxf(fmaf(-2.f, aF[r], sqqwE + sk.w), EPSf);
                float dF = __builtin_amdgcn_sqrtf(sF);
                p[r] = fmaf(de2, dF, fmaf(gl2, lH, p[r]));
            }
        }

        const char* vp = vtb + (size_t)kblk * 4096 + laneoff;
        s8v b00 = *(const s8v*)(vp);
        s8v b01 = *(const s8v*)(vp + 1024);
        s8v b10 = *(const s8v*)(vp + 2048);
        s8v b11 = *(const s8v*)(vp + 3072);

        float mt = p[0];
        #pragma unroll
        for (int r = 1; r < 16; r++) mt = fmaxf(mt, p[r]);
        mt = fmaxf(mt, __shfl_xor(mt, 32, 64));
        if (!__all(mt <= m_run + 8.f)) {
            float mnew = fmaxf(m_run, mt);
            float sc = exp2f(m_run - mnew);
            l_run *= sc;
            m_run = mnew;
            #pragma unroll
            for (int r = 0; r < 16; r++) {
                float s = __shfl(sc, RMAP(r) + h4, 64);
                o0[r] *= s; o1[r] *= s;
            }
        }
        float ps = 0.f;
        #pragma unroll
        for (int r = 0; r < 16; r++) { p[r] = exp2f(p[r] - m_run); ps += p[r]; }
        ps += __shfl_xor(ps, 32, 64);
        l_run += ps;

        unsigned int w0, w1, w2, w3, y0, y1, y2, y3;
        PKB(w0, p[0], p[1]);   PKB(w1, p[2], p[3]);
        PKB(w2, p[4], p[5]);   PKB(w3, p[6], p[7]);
        PKB(y0, p[8], p[9]);   PKB(y1, p[10], p[11]);
        PKB(y2, p[12], p[13]); PKB(y3, p[14], p[15]);
        SWL(w0, w2); SWL(w1, w3); SWL(y0, y2); SWL(y1, y3);
        int4 t1; t1.x = (int)w0; t1.y = (int)w1; t1.z = (int)w2; t1.w = (int)w3;
        int4 t2; t2.x = (int)y0; t2.y = (int)y1; t2.z = (int)y2; t2.w = (int)y3;
        s8v A1 = *(s8v*)&t1;
        s8v A2 = *(s8v*)&t2;

        __builtin_amdgcn_s_setprio(1);
        o0 = MFMA32x32(A1, b00, o0);
        o0 = MFMA32x32(A2, b10, o0);
        o1 = MFMA32x32(A1, b01, o1);
        o1 = MFMA32x32(A2, b11, o1);
        __builtin_amdgcn_s_setprio(0);
    }

    float* slotO0 = (float*)sm;
    float* slotO1 = (float*)(sm + 8192);
    float* slotM0 = (float*)(sm + 16384);
    float* slotM1 = (float*)(sm + 16896);

    __syncthreads();
    if (par >= 2) {
        float* so = (par == 2) ? slotO0 : slotO1;
        float* sM = (par == 2) ? slotM0 : slotM1;
        #pragma unroll
        for (int r = 0; r < 16; r++) {
            int qr = RMAP(r) + h4;
            so[qr * 64 + l31] = o0[r];
            so[qr * 64 + 32 + l31] = o1[r];
        }
        if (lane < 32) { sM[lane] = m_run; sM[32 + lane] = l_run; }
    }
    __syncthreads();
    if (par < 2) {
        float* so = (par == 0) ? slotO0 : slotO1;
        float* sM = (par == 0) ? slotM0 : slotM1;
        float m2 = sM[l31], l2 = sM[32 + l31];
        float M = fmaxf(m_run, m2);
        float s1 = exp2f(m_run - M), s2 = exp2f(m2 - M);
        l_run = l_run * s1 + l2 * s2;
        m_run = M;
        #pragma unroll
        for (int r = 0; r < 16; r++) {
            int qr = RMAP(r) + h4;
            float a = __shfl(s1, qr, 64), b = __shfl(s2, qr, 64);
            o0[r] = o0[r] * a + so[qr * 64 + l31] * b;
            o1[r] = o1[r] * a + so[qr * 64 + 32 + l31] * b;
        }
    }
    __syncthreads();
    if (par == 1) {
        #pragma unroll
        for (int r = 0; r < 16; r++) {
            int qr = RMAP(r) + h4;
            slotO0[qr * 64 + l31] = o0[r];
            slotO0[qr * 64 + 32 + l31] = o1[r];
        }
        if (lane < 32) { slotM0[lane] = m_run; slotM0[32 + lane] = l_run; }
    }
    __syncthreads();
    if (par == 0) {
        float m2 = slotM0[l31], l2 = slotM0[32 + l31];
        float M = fmaxf(m_run, m2);
        float s1 = exp2f(m_run - M), s2 = exp2f(m2 - M);
        float lt = l_run * s1 + l2 * s2;
        float inv = 1.f / lt;
        float a0 = s1 * inv, b0 = s2 * inv;
        #pragma unroll
        for (int r = 0; r < 16; r++) {
            int qr = RMAP(r) + h4;
            float a = __shfl(a0, qr, 64), b = __shfl(b0, qr, 64);
            float r0 = o0[r] * a + slotO0[qr * 64 + l31] * b;
            float r1 = o1[r] * a + slotO0[qr * 64 + 32 + l31] * b;
            size_t row = (size_t)bz * Nd + q0 + qr;
            aout[row * Dd + hh * 64 + l31] = __float2bfloat16(r0);
            aout[row * Dd + hh * 64 + 32 + l31] = __float2bfloat16(r1);
        }
    }
}

extern "C" void kernel_launch(void* const* d_in, const int* in_sizes, int n_in,
                              void* d_out, int out_size, void* d_ws, size_t ws_size,
                              hipStream_t stream) {
    const float* x    = (const float*)d_in[0];
    const int*   mask = (const int*)d_in[1];
    const float* WE   = (const float*)d_in[2];
    const float* bE   = (const float*)d_in[3];
    const float* WS   = (const float*)d_in[4];
    const float* bS   = (const float*)d_in[5];
    const float* WH   = (const float*)d_in[6];
    const float* bH   = (const float*)d_in[7];
    const float* Wrff = (const float*)d_in[8];
    const float* brff = (const float*)d_in[9];
    const float* alpha = (const float*)d_in[10];
    const float* beta  = (const float*)d_in[11];
    const float* gamma_ = (const float*)d_in[12];
    const float* delta = (const float*)d_in[13];
    const float* temperature = (const float*)d_in[14];
    const float* Wv = (const float*)d_in[15];
    const float* bv = (const float*)d_in[16];
    const float* Wo = (const float*)d_in[17];
    const float* bo = (const float*)d_in[18];

    char* ws = (char*)d_ws;
    unsigned short* wit = (unsigned short*)ws;               // 20971520
    float* sq  = (float*)(ws + 20971520);                    // 524288
    unsigned short* xb  = (unsigned short*)(ws + 21495808);  // 4194304
    unsigned short* wvb = (unsigned short*)(ws + 25690112);  // 2097152
    unsigned short* wob = (unsigned short*)(ws + 27787264);  // 2097152
    unsigned short* vt  = (unsigned short*)(ws + 29884416);  // 4194304
    __hip_bfloat16* aout = (__hip_bfloat16*)(ws + 34078720); // 4194304
    unsigned short* wfH = (unsigned short*)(ws + 34078720);            // 655360 B (dead before attn)
    unsigned short* wfL = (unsigned short*)(ws + 34078720 + 655360);   // 655360 B

    prep_kernel<<<dim3(2208), 256, 0, stream>>>(Wv, Wo, wvb, WE, WS, WH, Wrff, wfH, wfL);

    witness_kernel<<<dim3(8, 16, 2), 256, 0, stream>>>(
        x, mask, bE, bS, bH, brff, wfH, wfL, wit, sq, xb);

    gemm_bf16_kernel<1><<<dim3(16, 32), 256, 0, stream>>>(xb, wvb, bv, nullptr, vt);

    attn_kernel<<<dim3(1024), 256, 0, stream>>>(
        wit, sq, vt, alpha, beta, gamma_, delta, temperature, aout);

    gemm_bf16_kernel<0><<<dim3(16, 32), 256, 0, stream>>>(
        (const unsigned short*)aout, wob, bo, (float*)d_out, nullptr);
}